// Round 7
// baseline (1425.300 us; speedup 1.0000x reference)
//
#include <hip/hip_runtime.h>
#include <stdint.h>

#define BB 16384
#define ZZ 64
#define DD 66
#define NB 4     // batch rows per wave
#define WPB 4    // waves per block

// ---- ws float offsets (filled by prep kernel every launch) ----
#define OFF_SVMU 0        // [66][64] float2 (mult_u, sqrt(var_u)) -> 8448 floats
#define OFF_C0U  8448     // 64 : -0.5*sum_d(1+lv-var) per z
#define OFF_MG   8512     // 64
#define OFF_SVG  8576     // 64
#define OFF_C0G  8640     // 1

// Fold exps/constants once per launch (1 small block).
__global__ void prep_kernel(const float* __restrict__ mult_u, const float* __restrict__ logvar_u,
                            const float* __restrict__ mult_g, const float* __restrict__ logvar_g,
                            float* __restrict__ ws) {
  const int t = threadIdx.x;
  for (int i = t; i < DD*ZZ; i += 256) {
    ws[OFF_SVMU + 2*i]     = mult_u[i];
    ws[OFF_SVMU + 2*i + 1] = __expf(0.5f * logvar_u[i]);
  }
  if (t < ZZ) {
    float s = 0.f;
    for (int d = 0; d < DD; ++d) {
      const float lv = logvar_u[d*ZZ + t];
      s += 1.f + lv - __expf(lv);
    }
    ws[OFF_C0U + t] = -0.5f * s;
    ws[OFF_MG  + t] = mult_g[t];
    ws[OFF_SVG + t] = __expf(0.5f * logvar_g[t]);
  }
  if (t == 0) {
    float s = 0.f;
    for (int z = 0; z < ZZ; ++z) {
      const float lv = logvar_g[z];
      s += 1.f + lv - __expf(lv);
    }
    ws[OFF_C0G] = -0.5f * s;
  }
}

// Main: lane = z; wave w handles batch rows b0..b0+3. Everything fused.
__global__ __launch_bounds__(256, 2)
void disrnn_main(const float* __restrict__ latents, const float* __restrict__ obs,
                 const float* __restrict__ noise_u, const float* __restrict__ noise_g,
                 const float* __restrict__ z0, const float* __restrict__ W1,
                 const float* __restrict__ b1, const float* __restrict__ W2,
                 const float* __restrict__ b2, const float* __restrict__ W3,
                 const float* __restrict__ b3,
                 const float* __restrict__ Wc1, const float* __restrict__ bc1,
                 const float* __restrict__ Wc2, const float* __restrict__ bc2,
                 const float* __restrict__ Wc3, const float* __restrict__ bc3,
                 const float* __restrict__ ws, const int* __restrict__ t0p,
                 float* __restrict__ out) {
  float* out_y  = out;
  float* out_zt = out + BB*2;
  float* out_kg = out + BB*2 + BB*ZZ;
  float* out_ku = out + BB*2 + BB*ZZ + BB;

  __shared__ float s_x[WPB][NB][68];    // x rows (66 used)
  __shared__ float s_red[WPB][NB][64];  // tg^2 for kld_g
  __shared__ float s_zt[WPB][NB][64];   // fp32 z_tilde for choice MLP
  __shared__ float s_y1[WPB][2][2][32]; // [pass][half][j]
  __shared__ float s_y2[WPB][2][2][32];
  __shared__ float s_wc1[2048];
  __shared__ float s_wc2[1024];
  __shared__ float s_wc3[64];
  __shared__ float s_bc1[32], s_bc2[32], s_bc3[2];

  const int tid  = threadIdx.x;
  const int w    = tid >> 6;
  const int lane = tid & 63;
  const int b0   = (blockIdx.x * WPB + w) * NB;
  const int t0   = *t0p;

  // cooperative staging: choice weights -> LDS (read much later, wave-local)
  for (int idx = tid; idx < 2048; idx += 256) s_wc1[idx] = Wc1[idx];
  for (int idx = tid; idx < 1024; idx += 256) s_wc2[idx] = Wc2[idx];
  if (tid < 64) s_wc3[tid] = Wc3[tid];
  if (tid < 32) { s_bc1[tid] = bc1[tid]; s_bc2[tid] = bc2[tid]; }
  if (tid < 2)  s_bc3[tid] = bc3[tid];

  // stage x rows: x = [lat | obs]
#pragma unroll
  for (int i = 0; i < NB; ++i) {
    s_x[w][i][lane] = t0 ? z0[lane] : latents[(b0 + i)*ZZ + lane];
    if (lane < 2) s_x[w][i][ZZ + lane] = obs[(b0 + i)*2 + lane];
  }
  __syncthreads();

  const float2* __restrict__ svmu = (const float2*)(ws + OFF_SVMU);

  float acc[NB][16], kacc[NB];
  {
    const float4* bp = reinterpret_cast<const float4*>(b1 + lane*16);
    float b1r[16];
#pragma unroll
    for (int q = 0; q < 4; ++q) {
      const float4 v = bp[q];
      b1r[4*q] = v.x; b1r[4*q+1] = v.y; b1r[4*q+2] = v.z; b1r[4*q+3] = v.w;
    }
#pragma unroll
    for (int i = 0; i < NB; ++i) {
      kacc[i] = 0.f;
#pragma unroll
      for (int h = 0; h < 16; ++h) acc[i][h] = b1r[h];
    }
  }

  // ---- layer 1: 16 chunks of 4 d's, noise+sv prefetched (16 loads in flight) ----
  for (int c = 0; c < 16; ++c) {
    const int d0 = c * 4;
    float2 smb[4];
    float  nvb[4][NB];
#pragma unroll
    for (int u = 0; u < 4; ++u) {
      smb[u] = svmu[(d0 + u)*ZZ + lane];
#pragma unroll
      for (int i = 0; i < NB; ++i)
        nvb[u][i] = noise_u[((b0 + i)*DD + d0 + u)*ZZ + lane];
    }
#pragma unroll
    for (int u = 0; u < 4; ++u) {
      const int d = d0 + u;
      const float4* wp = reinterpret_cast<const float4*>(W1 + (lane*DD + d)*16);
      float wv[16];
#pragma unroll
      for (int q = 0; q < 4; ++q) {
        const float4 v = wp[q];
        wv[4*q] = v.x; wv[4*q+1] = v.y; wv[4*q+2] = v.z; wv[4*q+3] = v.w;
      }
#pragma unroll
      for (int i = 0; i < NB; ++i) {
        const float xv   = s_x[w][i][d];
        const float mean = xv * smb[u].x;
        const float xt   = fmaf(nvb[u][i], smb[u].y, mean);
        kacc[i] = fmaf(mean, mean, kacc[i]);
#pragma unroll
        for (int h = 0; h < 16; ++h) acc[i][h] = fmaf(xt, wv[h], acc[i][h]);
      }
    }
  }
  // ---- tail d = 64, 65 ----
  {
    float2 smb[2];
    float  nvb[2][NB];
#pragma unroll
    for (int u = 0; u < 2; ++u) {
      smb[u] = svmu[(64 + u)*ZZ + lane];
#pragma unroll
      for (int i = 0; i < NB; ++i)
        nvb[u][i] = noise_u[((b0 + i)*DD + 64 + u)*ZZ + lane];
    }
#pragma unroll
    for (int u = 0; u < 2; ++u) {
      const int d = 64 + u;
      const float4* wp = reinterpret_cast<const float4*>(W1 + (lane*DD + d)*16);
      float wv[16];
#pragma unroll
      for (int q = 0; q < 4; ++q) {
        const float4 v = wp[q];
        wv[4*q] = v.x; wv[4*q+1] = v.y; wv[4*q+2] = v.z; wv[4*q+3] = v.w;
      }
#pragma unroll
      for (int i = 0; i < NB; ++i) {
        const float xv   = s_x[w][i][d];
        const float mean = xv * smb[u].x;
        const float xt   = fmaf(nvb[u][i], smb[u].y, mean);
        kacc[i] = fmaf(mean, mean, kacc[i]);
#pragma unroll
        for (int h = 0; h < 16; ++h) acc[i][h] = fmaf(xt, wv[h], acc[i][h]);
      }
    }
  }

  // ---- per-row epilogue: layer2, layer3, gate, kld, z_tilde ----
  const float c0u_l = ws[OFF_C0U + lane];
  const float mg_l  = ws[OFF_MG + lane];
  const float svg_l = ws[OFF_SVG + lane];
  const float c0g   = ws[OFF_C0G];
#pragma unroll
  for (int i = 0; i < NB; ++i) {
    const int b = b0 + i;
    float h2[16];
    {
      const float4* bp = reinterpret_cast<const float4*>(b2 + lane*16);
#pragma unroll
      for (int q = 0; q < 4; ++q) {
        const float4 v = bp[q];
        h2[4*q] = v.x; h2[4*q+1] = v.y; h2[4*q+2] = v.z; h2[4*q+3] = v.w;
      }
    }
#pragma unroll
    for (int h = 0; h < 16; ++h) {
      const float hv = fmaxf(acc[i][h], 0.f);
      const float4* wp = reinterpret_cast<const float4*>(W2 + (lane*16 + h)*16);
#pragma unroll
      for (int q = 0; q < 4; ++q) {
        const float4 v = wp[q];
        h2[4*q]   = fmaf(hv, v.x, h2[4*q]);
        h2[4*q+1] = fmaf(hv, v.y, h2[4*q+1]);
        h2[4*q+2] = fmaf(hv, v.z, h2[4*q+2]);
        h2[4*q+3] = fmaf(hv, v.w, h2[4*q+3]);
      }
    }
    float o0 = b3[lane*2], o1 = b3[lane*2 + 1];
    {
      const float4* wp3 = reinterpret_cast<const float4*>(W3 + lane*32);
#pragma unroll
      for (int q = 0; q < 8; ++q) {
        const float4 v = wp3[q];
        const float hv0 = fmaxf(h2[2*q],     0.f);
        const float hv1 = fmaxf(h2[2*q + 1], 0.f);
        o0 = fmaf(hv0, v.x, fmaf(hv1, v.z, o0));
        o1 = fmaf(hv0, v.y, fmaf(hv1, v.w, o1));
      }
    }
    const float xl = s_x[w][i][lane];
    const float wg = 1.f / (1.f + __expf(-o1));
    const float nl = fmaf(wg, o0 - xl, xl);        // (1-w)*lat + u*w
    const float tg = mg_l * nl;
    const float zt = fmaf(noise_g[b*ZZ + lane], svg_l, tg);
    out_zt[b*ZZ + lane] = zt;
    out_ku[b*ZZ + lane] = fmaf(0.5f, kacc[i], c0u_l);
    s_red[w][i][lane] = tg * tg;
    s_zt[w][i][lane]  = zt;
  }

  // ---- kld_g (wave-local LDS reduce, deterministic) ----
  if (lane < NB) {
    float s = 0.f;
    for (int z = 0; z < ZZ; ++z) s += s_red[w][lane][z];
    out_kg[b0 + lane] = fmaf(0.5f, s, c0g);
  }

  // ---- choice MLP, fused & wave-local (2 rows per pass, lane = half*32 + j) ----
#pragma unroll
  for (int q = 0; q < 2; ++q) {           // pass q handles rows 2q, 2q+1
    const int p = lane >> 5;              // which row of the pair
    const int j = lane & 31;
    const int i = 2*q + p;
    float a0 = 0.f, a1 = 0.f;
#pragma unroll 8
    for (int z = 0; z < 64; z += 2) {
      a0 = fmaf(s_zt[w][i][z],     s_wc1[z*32 + j],       a0);
      a1 = fmaf(s_zt[w][i][z + 1], s_wc1[(z + 1)*32 + j], a1);
    }
    s_y1[w][q][p][j] = fmaxf(a0 + a1 + s_bc1[j], 0.f);
    float c0v = 0.f, c1v = 0.f;
#pragma unroll 8
    for (int h = 0; h < 32; h += 2) {
      c0v = fmaf(s_y1[w][q][p][h],     s_wc2[h*32 + j],       c0v);
      c1v = fmaf(s_y1[w][q][p][h + 1], s_wc2[(h + 1)*32 + j], c1v);
    }
    s_y2[w][q][p][j] = fmaxf(c0v + c1v + s_bc2[j], 0.f);
    if (lane < 4) {
      const int pp = lane >> 1, o = lane & 1;
      float s = s_bc3[o];
      for (int k = 0; k < 32; ++k) s = fmaf(s_y2[w][q][pp][k], s_wc3[2*k + o], s);
      out_y[(b0 + 2*q + pp)*2 + o] = s;
    }
  }
}

extern "C" void kernel_launch(void* const* d_in, const int* in_sizes, int n_in,
                              void* d_out, int out_size, void* d_ws, size_t ws_size,
                              hipStream_t stream) {
  const float* latents  = (const float*)d_in[0];
  const float* obs      = (const float*)d_in[1];
  const float* noise_u  = (const float*)d_in[2];
  const float* noise_g  = (const float*)d_in[3];
  const float* z0       = (const float*)d_in[4];
  const float* mult_u   = (const float*)d_in[5];
  const float* logvar_u = (const float*)d_in[6];
  const float* mult_g   = (const float*)d_in[7];
  const float* logvar_g = (const float*)d_in[8];
  const float* W1       = (const float*)d_in[9];
  const float* b1       = (const float*)d_in[10];
  const float* W2       = (const float*)d_in[11];
  const float* b2       = (const float*)d_in[12];
  const float* W3       = (const float*)d_in[13];
  const float* b3       = (const float*)d_in[14];
  const float* Wc1      = (const float*)d_in[15];
  const float* bc1      = (const float*)d_in[16];
  const float* Wc2      = (const float*)d_in[17];
  const float* bc2      = (const float*)d_in[18];
  const float* Wc3      = (const float*)d_in[19];
  const float* bc3      = (const float*)d_in[20];
  const int*  t0p       = (const int*)d_in[21];
  float* ws = (float*)d_ws;
  float* outp = (float*)d_out;

  prep_kernel<<<1, 256, 0, stream>>>(mult_u, logvar_u, mult_g, logvar_g, ws);
  disrnn_main<<<BB/(WPB*NB), 256, 0, stream>>>(latents, obs, noise_u, noise_g, z0,
                                               W1, b1, W2, b2, W3, b3,
                                               Wc1, bc1, Wc2, bc2, Wc3, bc3,
                                               ws, t0p, outp);
}